// Round 8
// baseline (52.573 us; speedup 1.0000x reference)
//
#include <hip/hip_runtime.h>
#include <math.h>

typedef float  f32x4  __attribute__((ext_vector_type(4)));
typedef short  bf16x8 __attribute__((ext_vector_type(8)));
typedef unsigned int u32x4 __attribute__((ext_vector_type(4)));

namespace {
constexpr int B = 8, N = 1024, Qn = 128, K = 16, M = N + Qn;  // M=1152
constexpr int GROUPS = M / 16;      // 72 row-groups (0..63 surface, 64..71 query)
constexpr int NBLK   = B * GROUPS;  // 576 blocks
constexpr int WPB    = 8;           // waves per block
constexpr int SLICE  = N / WPB;     // 128 n per wave
constexpr int CHUNKS = SLICE / 32;  // 4 chunks of 32 n
}

#define EXP2F(x) __builtin_amdgcn_exp2f(x)

// pack bf16-truncations of (a,b): low16 = trunc_bf16(a), high16 = trunc_bf16(b)
__device__ __forceinline__ unsigned pack_trunc(float a, float b) {
  return (__float_as_uint(a) >> 16) | (__float_as_uint(b) & 0xFFFF0000u);
}
// f32 value of trunc_bf16(x)
__device__ __forceinline__ float hi_part(float x) {
  return __uint_as_float(__float_as_uint(x) & 0xFFFF0000u);
}
__device__ __forceinline__ float sgpr_bc(float x) {
  return __uint_as_float(__builtin_amdgcn_readfirstlane(__float_as_uint(x)));
}

// ---------------------------------------------------------------------------
// Block = (batch b, 16-row group g). 8 waves, each owns a 128-n slice.
// Split-precision bf16 MFMA accumulation:
//   A rows: 0 = t_hi, 1 = t_lo, 2 = ones, 3..15 = 0   (exact bit-split of t)
//   two MFMAs per (k, chunk): B = E_hi then B = E_lo  (exact bit-split of e)
//   wsum = D[0][m]+D[1][m] = sum t~ * e~ ;  nrm = D[2][m] = sum e~
//   (t~, e~ accurate to ~2^-16 relative -> LN-safe)
// D layout (m89/m91): col = lane&15, row = (lane>>4)*4 + reg.
// ---------------------------------------------------------------------------
__global__ __launch_bounds__(512) void IvySPT_main(
    const float* __restrict__ lm_s, const float* __restrict__ ttm_s,
    const float* __restrict__ tv_s, const float* __restrict__ lm_q,
    const float* __restrict__ ttm_q, const float* __restrict__ lsk,
    const float* __restrict__ ln_s_w, const float* __restrict__ ln_s_b,
    const float* __restrict__ ln_q_w, const float* __restrict__ ln_q_b,
    const float* __restrict__ pls_p,
    float* __restrict__ out)
{
  __shared__ float sC[2][K];
  __shared__ float sRed[WPB][16][2 * K + 1];

  if (threadIdx.x < K) {
    const int k = threadIdx.x;
    float s0 = expf(lsk[2 * k + 0]);
    float s1 = expf(lsk[2 * k + 1]);
    float tr = s0 + s1;
    float x  = (float)(k + 1) / (float)(K + 1);
    float bw = erfinvf(x) * 1.41421356237309504880f;
    float denom = tr * 2.0f * bw * bw;
    const float LOG2E = 1.44269504088896340736f;
    sC[0][k] = -s0 * LOG2E / denom;   // cA_k (pairs with dx^2)
    sC[1][k] = -s1 * LOG2E / denom;   // cB_k (pairs with dy^2)
  }
  __syncthreads();

  const int l  = threadIdx.x & 63;
  const int w  = threadIdx.x >> 6;
  const int b  = blockIdx.x / GROUPS;
  const int g  = blockIdx.x % GROUPS;
  const int mi = l & 15;   // lane's m within group (B-fragment col)
  const int jc = l >> 4;   // lane's k-slot window: jc*8 .. jc*8+7

  const int mg = g * 16 + mi;
  float xm, ym;
  if (g < 64) { xm = lm_s[b * N + mg];        ym = ttm_s[b * N + mg]; }
  else        { xm = lm_q[b * Qn + (mg - N)]; ym = ttm_q[b * Qn + (mg - N)]; }

  float cA[K], cB[K];
#pragma unroll
  for (int k = 0; k < K; k++) { cA[k] = sgpr_bc(sC[0][k]); cB[k] = sgpr_bc(sC[1][k]); }

  f32x4 acc[K];
#pragma unroll
  for (int k = 0; k < K; k++) acc[k] = f32x4{0.f, 0.f, 0.f, 0.f};

  const float* xs = lm_s  + b * N;
  const float* ys = ttm_s + b * N;
  const float* tv = tv_s  + b * N;

#pragma unroll 1
  for (int c = 0; c < CHUNKS; ++c) {
    const int nb = w * SLICE + c * 32 + jc * 8;
    float4 x0 = *(const float4*)(xs + nb);
    float4 x1 = *(const float4*)(xs + nb + 4);
    float4 y0 = *(const float4*)(ys + nb);
    float4 y1 = *(const float4*)(ys + nb + 4);
    float4 t0 = *(const float4*)(tv + nb);
    float4 t1 = *(const float4*)(tv + nb + 4);

    float dx2[8], dy2[8];
    {
      float d;
      d = xm - x0.x; dx2[0] = d * d;  d = xm - x0.y; dx2[1] = d * d;
      d = xm - x0.z; dx2[2] = d * d;  d = xm - x0.w; dx2[3] = d * d;
      d = xm - x1.x; dx2[4] = d * d;  d = xm - x1.y; dx2[5] = d * d;
      d = xm - x1.z; dx2[6] = d * d;  d = xm - x1.w; dx2[7] = d * d;
      d = ym - y0.x; dy2[0] = d * d;  d = ym - y0.y; dy2[1] = d * d;
      d = ym - y0.z; dy2[2] = d * d;  d = ym - y0.w; dy2[3] = d * d;
      d = ym - y1.x; dy2[4] = d * d;  d = ym - y1.y; dy2[5] = d * d;
      d = ym - y1.z; dy2[6] = d * d;  d = ym - y1.w; dy2[7] = d * d;
    }

    // A-fragment: exact bit-split of t. row0 = t_hi, row1 = t_lo, row2 = 1.
    u32x4 afh, afl;
    {
      unsigned th0 = pack_trunc(t0.x, t0.y);
      unsigned th1 = pack_trunc(t0.z, t0.w);
      unsigned th2 = pack_trunc(t1.x, t1.y);
      unsigned th3 = pack_trunc(t1.z, t1.w);
      float tl0 = t0.x - hi_part(t0.x), tl1 = t0.y - hi_part(t0.y);
      float tl2 = t0.z - hi_part(t0.z), tl3 = t0.w - hi_part(t0.w);
      float tl4 = t1.x - hi_part(t1.x), tl5 = t1.y - hi_part(t1.y);
      float tl6 = t1.z - hi_part(t1.z), tl7 = t1.w - hi_part(t1.w);
      unsigned tq0 = pack_trunc(tl0, tl1);
      unsigned tq1 = pack_trunc(tl2, tl3);
      unsigned tq2 = pack_trunc(tl4, tl5);
      unsigned tq3 = pack_trunc(tl6, tl7);
      const unsigned ones = 0x3F803F80u;
      afh.x = (mi == 0) ? th0 : ((mi == 1) ? tq0 : ((mi == 2) ? ones : 0u));
      afh.y = (mi == 0) ? th1 : ((mi == 1) ? tq1 : ((mi == 2) ? ones : 0u));
      afh.z = (mi == 0) ? th2 : ((mi == 1) ? tq2 : ((mi == 2) ? ones : 0u));
      afh.w = (mi == 0) ? th3 : ((mi == 1) ? tq3 : ((mi == 2) ? ones : 0u));
    }
    bf16x8 A = __builtin_bit_cast(bf16x8, afh);
    (void)afl;

#pragma unroll
    for (int k = 0; k < K; k++) {
      float e0 = EXP2F(fmaf(dy2[0], cB[k], dx2[0] * cA[k]));
      float e1 = EXP2F(fmaf(dy2[1], cB[k], dx2[1] * cA[k]));
      float e2 = EXP2F(fmaf(dy2[2], cB[k], dx2[2] * cA[k]));
      float e3 = EXP2F(fmaf(dy2[3], cB[k], dx2[3] * cA[k]));
      float e4 = EXP2F(fmaf(dy2[4], cB[k], dx2[4] * cA[k]));
      float e5 = EXP2F(fmaf(dy2[5], cB[k], dx2[5] * cA[k]));
      float e6 = EXP2F(fmaf(dy2[6], cB[k], dx2[6] * cA[k]));
      float e7 = EXP2F(fmaf(dy2[7], cB[k], dx2[7] * cA[k]));
      // exact bit-split e = e_hi + (e - e_hi); both halves bf16-truncated
      u32x4 ehi, elo;
      ehi.x = pack_trunc(e0, e1);
      ehi.y = pack_trunc(e2, e3);
      ehi.z = pack_trunc(e4, e5);
      ehi.w = pack_trunc(e6, e7);
      float l0 = e0 - hi_part(e0), l1 = e1 - hi_part(e1);
      float l2 = e2 - hi_part(e2), l3 = e3 - hi_part(e3);
      float l4 = e4 - hi_part(e4), l5 = e5 - hi_part(e5);
      float l6 = e6 - hi_part(e6), l7 = e7 - hi_part(e7);
      elo.x = pack_trunc(l0, l1);
      elo.y = pack_trunc(l2, l3);
      elo.z = pack_trunc(l4, l5);
      elo.w = pack_trunc(l6, l7);
      bf16x8 Eh = __builtin_bit_cast(bf16x8, ehi);
      bf16x8 El = __builtin_bit_cast(bf16x8, elo);
      acc[k] = __builtin_amdgcn_mfma_f32_16x16x32_bf16(A, Eh, acc[k], 0, 0, 0);
      acc[k] = __builtin_amdgcn_mfma_f32_16x16x32_bf16(A, El, acc[k], 0, 0, 0);
    }
  }

  // D: col=lane&15, row=(lane>>4)*4+reg. Lanes 0-15: reg0=row0 (t_hi*e),
  // reg1=row1 (t_lo*e), reg2=row2 (sum e).
  if (l < 16) {
#pragma unroll
    for (int k = 0; k < K; k++) {
      sRed[w][l][2 * k]     = acc[k].x + acc[k].y;  // wsum
      sRed[w][l][2 * k + 1] = acc[k].z;             // nrm
    }
  }
  __syncthreads();

  if (threadIdx.x < 256) {
    const int kk = threadIdx.x & 15;
    const int m  = threadIdx.x >> 4;
    float sw = 0.f, sn = 0.f;
#pragma unroll
    for (int ww = 0; ww < WPB; ww++) {
      sw += sRed[ww][m][2 * kk];
      sn += sRed[ww][m][2 * kk + 1];
    }
    float emb = sw / sn;

    // LayerNorm over K=16 within each 16-lane group
    float s1 = emb;
    s1 += __shfl_xor(s1, 1); s1 += __shfl_xor(s1, 2);
    s1 += __shfl_xor(s1, 4); s1 += __shfl_xor(s1, 8);
    float mean = s1 * (1.f / 16.f);
    float dv = emb - mean;
    float s2 = dv * dv;
    s2 += __shfl_xor(s2, 1); s2 += __shfl_xor(s2, 2);
    s2 += __shfl_xor(s2, 4); s2 += __shfl_xor(s2, 8);
    float inv = rsqrtf(s2 * (1.f / 16.f) + 1e-5f);

    const int row = g * 16 + m;
    float lw, lb, cmx, cmy;
    if (g < 64) {
      lw = ln_s_w[kk]; lb = ln_s_b[kk];
      cmx = lm_s[b * N + row]; cmy = ttm_s[b * N + row];
    } else {
      lw = ln_q_w[kk]; lb = ln_q_b[kk];
      cmx = lm_q[b * Qn + (row - N)]; cmy = ttm_q[b * Qn + (row - N)];
    }
    float normed = dv * inv * lw + lb;

    // Positional embedding: kk = 4*i + c; c<2 -> x else y; c odd -> cos.
    float pls = pls_p[0];
    float invdiv = expf(-pls * (float)(kk >> 2) * 0.25f);
    float cv  = (kk & 2) ? cmy : cmx;
    float arg = cv * invdiv;
    float pe  = (kk & 1) ? cosf(arg) : sinf(arg);
    float val = fmaf(pe, 1.41421356237309504880f, normed);

    out[((size_t)(b * M + row)) * K + kk] = val;
  }
}

extern "C" void kernel_launch(void* const* d_in, const int* in_sizes, int n_in,
                              void* d_out, int out_size, void* d_ws, size_t ws_size,
                              hipStream_t stream) {
  const float* lm_s   = (const float*)d_in[0];
  const float* ttm_s  = (const float*)d_in[1];
  const float* tv_s   = (const float*)d_in[2];
  const float* lm_q   = (const float*)d_in[3];
  const float* ttm_q  = (const float*)d_in[4];
  const float* lsk    = (const float*)d_in[5];
  const float* ln_s_w = (const float*)d_in[6];
  const float* ln_s_b = (const float*)d_in[7];
  const float* ln_q_w = (const float*)d_in[8];
  const float* ln_q_b = (const float*)d_in[9];
  const float* pls    = (const float*)d_in[10];

  float* out = (float*)d_out;

  hipLaunchKernelGGL(IvySPT_main, dim3(NBLK), dim3(512), 0, stream,
                     lm_s, ttm_s, tv_s, lm_q, ttm_q, lsk,
                     ln_s_w, ln_s_b, ln_q_w, ln_q_b, pls, out);
}